// Round 1
// baseline (350.106 us; speedup 1.0000x reference)
//
#include <hip/hip_runtime.h>
#include <hip/hip_bf16.h>
#include <stdint.h>

#define D_MODEL 1024
#define N_STATE 16
#define BATCH   4
#define SEQ     2048
#define M_ROWS  (BATCH*SEQ)      // 8192
#define H_FFN   (4*D_MODEL)      // 4096
#define NCHUNK  32
#define TCHUNK  (SEQ/NCHUNK)     // 64

typedef __attribute__((ext_vector_type(8))) short short8;
typedef __attribute__((ext_vector_type(4))) float f32x4;

// ---------- helpers ----------
__device__ __forceinline__ unsigned short f2bf(float f) {
  // round-to-nearest-even fp32 -> bf16 (inputs are never NaN here)
  unsigned int u = __builtin_bit_cast(unsigned int, f);
  u += 0x7FFFu + ((u >> 16) & 1u);
  return (unsigned short)(u >> 16);
}

__device__ __forceinline__ void gload_lds16(const void* g, void* l) {
  __builtin_amdgcn_global_load_lds(
      (const __attribute__((address_space(1))) void*)g,
      (__attribute__((address_space(3))) void*)l,
      16, 0, 0);
}

// ---------- fp32 -> bf16 weight conversion ----------
__global__ __launch_bounds__(256)
void cvt_bf16(const float* __restrict__ in, unsigned short* __restrict__ out, int n4) {
  int i = blockIdx.x * 256 + threadIdx.x;
  if (i >= n4) return;
  float4 v = reinterpret_cast<const float4*>(in)[i];
  ushort4 o = { f2bf(v.x), f2bf(v.y), f2bf(v.z), f2bf(v.w) };
  reinterpret_cast<ushort4*>(out)[i] = o;
}

// ---------- LayerNorm (one block per row, 256 thr x 4 elems) ----------
template<bool BF16OUT>
__global__ __launch_bounds__(256)
void ln_kernel(const float* __restrict__ in, const float* __restrict__ gamma,
               const float* __restrict__ beta, void* __restrict__ outp) {
  const int row = blockIdx.x;
  const int tid = threadIdx.x;
  const float4 v = reinterpret_cast<const float4*>(in + (size_t)row * D_MODEL)[tid];
  float s  = v.x + v.y + v.z + v.w;
  float ss = v.x*v.x + v.y*v.y + v.z*v.z + v.w*v.w;
  #pragma unroll
  for (int o = 32; o > 0; o >>= 1) {
    s  += __shfl_down(s, o, 64);
    ss += __shfl_down(ss, o, 64);
  }
  __shared__ float red[8];
  const int wv = tid >> 6;
  if ((tid & 63) == 0) { red[wv] = s; red[4 + wv] = ss; }
  __syncthreads();
  s  = red[0] + red[1] + red[2] + red[3];
  ss = red[4] + red[5] + red[6] + red[7];
  const float mu  = s * (1.0f / D_MODEL);
  const float inv = rsqrtf(ss * (1.0f / D_MODEL) - mu * mu + 1e-5f);
  const float4 g4 = reinterpret_cast<const float4*>(gamma)[tid];
  const float4 b4 = reinterpret_cast<const float4*>(beta)[tid];
  const float o0 = (v.x - mu) * inv * g4.x + b4.x;
  const float o1 = (v.y - mu) * inv * g4.y + b4.y;
  const float o2 = (v.z - mu) * inv * g4.z + b4.z;
  const float o3 = (v.w - mu) * inv * g4.w + b4.w;
  if constexpr (BF16OUT) {
    ushort4 o = { f2bf(o0), f2bf(o1), f2bf(o2), f2bf(o3) };
    reinterpret_cast<ushort4*>((unsigned short*)outp + (size_t)row * D_MODEL)[tid] = o;
  } else {
    float4 o = { o0, o1, o2, o3 };
    reinterpret_cast<float4*>((float*)outp + (size_t)row * D_MODEL)[tid] = o;
  }
}

// ---------- SSM scan, chunked (3 phases) ----------
// phase 1: per (b, chunk, d): local scan from h=0, store h_end
__global__ __launch_bounds__(256)
void scan_phase1(const float* __restrict__ xn, const float* __restrict__ A_log,
                 const float* __restrict__ B_mat, float* __restrict__ hend) {
  const int d = blockIdx.x * 256 + threadIdx.x;
  const int c = blockIdx.y;
  const int b = blockIdx.z;
  float a[16], Bm[16], h[16];
  const float4* Ar = reinterpret_cast<const float4*>(A_log + d * 16);
  const float4* Br = reinterpret_cast<const float4*>(B_mat + d * 16);
  #pragma unroll
  for (int i = 0; i < 4; i++) {
    const float4 av = Ar[i], bv = Br[i];
    a[4*i+0]=av.x; a[4*i+1]=av.y; a[4*i+2]=av.z; a[4*i+3]=av.w;
    Bm[4*i+0]=bv.x; Bm[4*i+1]=bv.y; Bm[4*i+2]=bv.z; Bm[4*i+3]=bv.w;
  }
  #pragma unroll
  for (int n = 0; n < 16; n++) { a[n] = 1.0f/(1.0f+__expf(-a[n])); h[n] = 0.0f; }

  const float* xp = xn + ((size_t)b * SEQ + (size_t)c * TCHUNK) * D_MODEL + d;
  float xb0 = xp[0], xb1 = xp[D_MODEL], xb2 = xp[2*D_MODEL], xb3 = xp[3*D_MODEL];
  for (int t = 0; t < TCHUNK; t += 4) {
    const float xc0 = xb0, xc1 = xb1, xc2 = xb2, xc3 = xb3;
    if (t + 4 < TCHUNK) {
      const float* xq = xp + (size_t)(t + 4) * D_MODEL;
      xb0 = xq[0]; xb1 = xq[D_MODEL]; xb2 = xq[2*D_MODEL]; xb3 = xq[3*D_MODEL];
    }
    #pragma unroll
    for (int n = 0; n < 16; n++) h[n] = a[n]*h[n] + Bm[n]*xc0;
    #pragma unroll
    for (int n = 0; n < 16; n++) h[n] = a[n]*h[n] + Bm[n]*xc1;
    #pragma unroll
    for (int n = 0; n < 16; n++) h[n] = a[n]*h[n] + Bm[n]*xc2;
    #pragma unroll
    for (int n = 0; n < 16; n++) h[n] = a[n]*h[n] + Bm[n]*xc3;
  }
  float* hp = hend + (((size_t)b * NCHUNK + c) * D_MODEL + d) * 16;
  #pragma unroll
  for (int i = 0; i < 4; i++) {
    float4 o = { h[4*i+0], h[4*i+1], h[4*i+2], h[4*i+3] };
    reinterpret_cast<float4*>(hp)[i] = o;
  }
}

// phase 2: per (b, d, n): sequential carry combine across chunks
__global__ __launch_bounds__(256)
void scan_phase2(const float* __restrict__ A_log, const float* __restrict__ hend,
                 float* __restrict__ carry) {
  const int idx = blockIdx.x * 256 + threadIdx.x;   // over BATCH*D_MODEL*16
  const int n = idx & 15;
  const int d = (idx >> 4) & (D_MODEL - 1);
  const int b = idx >> 14;
  const float a = 1.0f/(1.0f+__expf(-A_log[d*16+n]));
  float aT = a;
  #pragma unroll
  for (int i = 0; i < 6; i++) aT *= aT;   // a^64 = a^TCHUNK
  float cv = 0.0f;
  for (int c = 0; c < NCHUNK; c++) {
    const size_t off = (((size_t)b * NCHUNK + c) * D_MODEL + d) * 16 + n;
    carry[off] = cv;
    cv = aT * cv + hend[off];
  }
}

// phase 3: replay with carry, y = C.h + D*x, silu, bf16 store
__global__ __launch_bounds__(256)
void scan_phase3(const float* __restrict__ xn, const float* __restrict__ A_log,
                 const float* __restrict__ B_mat, const float* __restrict__ C_mat,
                 const float* __restrict__ D_vec, const float* __restrict__ carry,
                 unsigned short* __restrict__ ybf) {
  const int d = blockIdx.x * 256 + threadIdx.x;
  const int c = blockIdx.y;
  const int b = blockIdx.z;
  float a[16], Bm[16], Cm[16], h[16];
  const float4* Ar = reinterpret_cast<const float4*>(A_log + d * 16);
  const float4* Br = reinterpret_cast<const float4*>(B_mat + d * 16);
  const float4* Cr = reinterpret_cast<const float4*>(C_mat + d * 16);
  const float4* Hr = reinterpret_cast<const float4*>(carry + (((size_t)b * NCHUNK + c) * D_MODEL + d) * 16);
  #pragma unroll
  for (int i = 0; i < 4; i++) {
    const float4 av = Ar[i], bv = Br[i], cv = Cr[i], hv = Hr[i];
    a[4*i+0]=av.x; a[4*i+1]=av.y; a[4*i+2]=av.z; a[4*i+3]=av.w;
    Bm[4*i+0]=bv.x; Bm[4*i+1]=bv.y; Bm[4*i+2]=bv.z; Bm[4*i+3]=bv.w;
    Cm[4*i+0]=cv.x; Cm[4*i+1]=cv.y; Cm[4*i+2]=cv.z; Cm[4*i+3]=cv.w;
    h[4*i+0]=hv.x; h[4*i+1]=hv.y; h[4*i+2]=hv.z; h[4*i+3]=hv.w;
  }
  #pragma unroll
  for (int n = 0; n < 16; n++) a[n] = 1.0f/(1.0f+__expf(-a[n]));
  const float Dv = D_vec[d];

  const float* xp = xn + ((size_t)b * SEQ + (size_t)c * TCHUNK) * D_MODEL + d;
  unsigned short* yp = ybf + ((size_t)b * SEQ + (size_t)c * TCHUNK) * D_MODEL + d;
  float xb0 = xp[0], xb1 = xp[D_MODEL], xb2 = xp[2*D_MODEL], xb3 = xp[3*D_MODEL];
  for (int t = 0; t < TCHUNK; t += 4) {
    const float xc0 = xb0, xc1 = xb1, xc2 = xb2, xc3 = xb3;
    if (t + 4 < TCHUNK) {
      const float* xq = xp + (size_t)(t + 4) * D_MODEL;
      xb0 = xq[0]; xb1 = xq[D_MODEL]; xb2 = xq[2*D_MODEL]; xb3 = xq[3*D_MODEL];
    }
    float y;
    #define SCAN_STEP(XC, TT)                                              \
      y = Dv * (XC);                                                       \
      _Pragma("unroll")                                                    \
      for (int n = 0; n < 16; n++) {                                       \
        h[n] = a[n]*h[n] + Bm[n]*(XC);                                     \
        y += Cm[n]*h[n];                                                   \
      }                                                                    \
      yp[(size_t)(t+(TT))*D_MODEL] = f2bf(y / (1.0f + __expf(-y)));
    SCAN_STEP(xc0, 0)
    SCAN_STEP(xc1, 1)
    SCAN_STEP(xc2, 2)
    SCAN_STEP(xc3, 3)
    #undef SCAN_STEP
  }
}

// ---------- bf16 MFMA GEMM: C[M,N] = epilogue(A[M,K] @ Bt[N,K]^T + bias) ----------
// 128x128 tile, BK=32, 4 waves (2x2), 4x4 16x16x32 fragments per wave (m97 structure)
template<int ACT, bool RES, typename OutT>
__global__ __launch_bounds__(256)
void gemm_bt(const unsigned short* __restrict__ A, const unsigned short* __restrict__ Bt,
             const float* __restrict__ bias, const float* __restrict__ res,
             OutT* __restrict__ C, int M, int N, int K) {
  __shared__ unsigned short As[128*32];
  __shared__ unsigned short Bs[128*32];
  const int tid  = threadIdx.x;
  const int lane = tid & 63;
  const int wave = tid >> 6;
  const int wr = wave >> 1;
  const int wc = wave & 1;
  const int bm = blockIdx.y * 128;
  const int bn = blockIdx.x * 128;

  f32x4 acc[4][4] = {};

  // staging: wave handles 2 segments of 16 rows; lane l -> row l/4, 16B chunk l%4
  const int seg0 = wave * 2, seg1 = wave * 2 + 1;
  const int srow = lane >> 2;
  const int skq  = (lane & 3) * 8;
  const unsigned short* Ag0 = A  + (size_t)(bm + seg0*16 + srow) * K + skq;
  const unsigned short* Ag1 = A  + (size_t)(bm + seg1*16 + srow) * K + skq;
  const unsigned short* Bg0 = Bt + (size_t)(bn + seg0*16 + srow) * K + skq;
  const unsigned short* Bg1 = Bt + (size_t)(bn + seg1*16 + srow) * K + skq;
  unsigned short* Al0 = &As[seg0 * 512];
  unsigned short* Al1 = &As[seg1 * 512];
  unsigned short* Bl0 = &Bs[seg0 * 512];
  unsigned short* Bl1 = &Bs[seg1 * 512];

  const int ar0 = (wr*64 + (lane & 15)) * 32 + (lane >> 4) * 8;
  const int br0 = (wc*64 + (lane & 15)) * 32 + (lane >> 4) * 8;

  for (int k0 = 0; k0 < K; k0 += 32) {
    gload_lds16(Ag0 + k0, Al0);
    gload_lds16(Ag1 + k0, Al1);
    gload_lds16(Bg0 + k0, Bl0);
    gload_lds16(Bg1 + k0, Bl1);
    __syncthreads();   // drains vmcnt before ds_read
    short8 af[4], bfr[4];
    #pragma unroll
    for (int m = 0; m < 4; m++)
      af[m] = *reinterpret_cast<const short8*>(&As[ar0 + m*16*32]);
    #pragma unroll
    for (int n = 0; n < 4; n++)
      bfr[n] = *reinterpret_cast<const short8*>(&Bs[br0 + n*16*32]);
    #pragma unroll
    for (int m = 0; m < 4; m++)
      #pragma unroll
      for (int n = 0; n < 4; n++)
        acc[m][n] = __builtin_amdgcn_mfma_f32_16x16x32_bf16(af[m], bfr[n], acc[m][n], 0, 0, 0);
    __syncthreads();
  }

  // epilogue: D row=(lane>>4)*4+r, col=lane&15
  const int fr = (lane >> 4) * 4;
  const int fc = lane & 15;
  #pragma unroll
  for (int n = 0; n < 4; n++) {
    const int col = bn + wc*64 + n*16 + fc;
    const float bv = bias[col];
    #pragma unroll
    for (int m = 0; m < 4; m++) {
      const int row0 = bm + wr*64 + m*16 + fr;
      #pragma unroll
      for (int r = 0; r < 4; r++) {
        const size_t idx = (size_t)(row0 + r) * N + col;
        float v = acc[m][n][r] + bv;
        if (ACT == 1) v = 0.5f * v * (1.0f + erff(v * 0.70710678118f));  // exact GELU
        if (RES) v += res[idx];
        if constexpr (sizeof(OutT) == 2) C[idx] = (OutT)f2bf(v);
        else                             C[idx] = v;
      }
    }
  }
}

// ---------- launch ----------
extern "C" void kernel_launch(void* const* d_in, const int* in_sizes, int n_in,
                              void* d_out, int out_size, void* d_ws, size_t ws_size,
                              hipStream_t stream) {
  const float* x      = (const float*)d_in[0];
  const float* ln_w   = (const float*)d_in[1];
  const float* ln_b   = (const float*)d_in[2];
  const float* A_log  = (const float*)d_in[3];
  const float* B_mat  = (const float*)d_in[4];
  const float* C_mat  = (const float*)d_in[5];
  const float* D_vec  = (const float*)d_in[6];
  const float* out_w  = (const float*)d_in[7];
  const float* out_b  = (const float*)d_in[8];
  const float* ln2_w  = (const float*)d_in[9];
  const float* ln2_b  = (const float*)d_in[10];
  const float* ffn1_w = (const float*)d_in[11];
  const float* ffn1_b = (const float*)d_in[12];
  const float* ffn2_w = (const float*)d_in[13];
  const float* ffn2_b = (const float*)d_in[14];
  float* out = (float*)d_out;

  char* ws = (char*)d_ws;
  const size_t MB = 1u << 20;
  float*          xn    = (float*)(ws);              // 32MB; later reused as x1
  unsigned short* ybf   = (unsigned short*)(ws + 32*MB);   // 16MB; later reused as xn2
  unsigned short* hdn   = (unsigned short*)(ws + 48*MB);   // 64MB
  unsigned short* w1b   = (unsigned short*)(ws + 112*MB);  // 2MB
  unsigned short* w2b   = (unsigned short*)(ws + 114*MB);  // 8MB
  unsigned short* w3b   = (unsigned short*)(ws + 122*MB);  // 8MB
  float*          hend  = (float*)(ws + 130*MB);     // 8MB
  float*          carry = (float*)(ws + 138*MB);     // 8MB

  // weights -> bf16
  cvt_bf16<<<(D_MODEL*D_MODEL/4)/256, 256, 0, stream>>>(out_w,  w1b, D_MODEL*D_MODEL/4);
  cvt_bf16<<<(H_FFN*D_MODEL/4)/256,  256, 0, stream>>>(ffn1_w, w2b, H_FFN*D_MODEL/4);
  cvt_bf16<<<(H_FFN*D_MODEL/4)/256,  256, 0, stream>>>(ffn2_w, w3b, H_FFN*D_MODEL/4);

  // LN1: xn = LN(x) fp32
  ln_kernel<false><<<M_ROWS, 256, 0, stream>>>(x, ln_w, ln_b, xn);

  // SSM scan -> ybf = silu(y) bf16
  dim3 gscan(D_MODEL/256, NCHUNK, BATCH);
  scan_phase1<<<gscan, 256, 0, stream>>>(xn, A_log, B_mat, hend);
  scan_phase2<<<(BATCH*D_MODEL*N_STATE)/256, 256, 0, stream>>>(A_log, hend, carry);
  scan_phase3<<<gscan, 256, 0, stream>>>(xn, A_log, B_mat, C_mat, D_vec, carry, ybf);

  // GEMM1: x1 = x + ybf @ out_w^T + out_b   (fp32, into xn buffer)
  dim3 gg1(D_MODEL/128, M_ROWS/128);
  gemm_bt<0, true, float><<<gg1, 256, 0, stream>>>(ybf, w1b, out_b, x, xn,
                                                   M_ROWS, D_MODEL, D_MODEL);
  // LN2: xn2 = LN(x1) bf16 (into ybf buffer)
  ln_kernel<true><<<M_ROWS, 256, 0, stream>>>(xn, ln2_w, ln2_b, ybf);

  // GEMM2: hdn = gelu(xn2 @ ffn1^T + ffn1_b) bf16
  dim3 gg2(H_FFN/128, M_ROWS/128);
  gemm_bt<1, false, unsigned short><<<gg2, 256, 0, stream>>>(ybf, w2b, ffn1_b, nullptr, hdn,
                                                             M_ROWS, H_FFN, D_MODEL);
  // GEMM3: out = x1 + hdn @ ffn2^T + ffn2_b (fp32)
  gemm_bt<0, true, float><<<gg1, 256, 0, stream>>>(hdn, w3b, ffn2_b, xn, out,
                                                   M_ROWS, D_MODEL, H_FFN);
}

// Round 2
// 324.362 us; speedup vs baseline: 1.0794x; 1.0794x over previous
//
#include <hip/hip_runtime.h>
#include <hip/hip_bf16.h>
#include <stdint.h>

#define D_MODEL 1024
#define N_STATE 16
#define BATCH   4
#define SEQ     2048
#define M_ROWS  (BATCH*SEQ)      // 8192
#define H_FFN   (4*D_MODEL)      // 4096
#define NCHUNK  32
#define TCHUNK  (SEQ/NCHUNK)     // 64

typedef __attribute__((ext_vector_type(8))) short short8;
typedef __attribute__((ext_vector_type(4))) float f32x4;

// ---------- helpers ----------
__device__ __forceinline__ unsigned short f2bf(float f) {
  unsigned int u = __builtin_bit_cast(unsigned int, f);
  u += 0x7FFFu + ((u >> 16) & 1u);
  return (unsigned short)(u >> 16);
}

__device__ __forceinline__ void gload_lds16(const void* g, void* l) {
  __builtin_amdgcn_global_load_lds(
      (const __attribute__((address_space(1))) void*)g,
      (__attribute__((address_space(3))) void*)l,
      16, 0, 0);
}

// ---------- fp32 -> bf16 weight conversion ----------
__global__ __launch_bounds__(256)
void cvt_bf16(const float* __restrict__ in, unsigned short* __restrict__ out, int n4) {
  int i = blockIdx.x * 256 + threadIdx.x;
  if (i >= n4) return;
  float4 v = reinterpret_cast<const float4*>(in)[i];
  ushort4 o = { f2bf(v.x), f2bf(v.y), f2bf(v.z), f2bf(v.w) };
  reinterpret_cast<ushort4*>(out)[i] = o;
}

// ---------- LN stats only: per row -> (mu, inv_sigma) ----------
__global__ __launch_bounds__(256)
void ln_stats(const float* __restrict__ in, float2* __restrict__ stats) {
  const int row = blockIdx.x;
  const int tid = threadIdx.x;
  const float4 v = reinterpret_cast<const float4*>(in + (size_t)row * D_MODEL)[tid];
  float s  = v.x + v.y + v.z + v.w;
  float ss = v.x*v.x + v.y*v.y + v.z*v.z + v.w*v.w;
  #pragma unroll
  for (int o = 32; o > 0; o >>= 1) {
    s  += __shfl_down(s, o, 64);
    ss += __shfl_down(ss, o, 64);
  }
  __shared__ float red[8];
  const int wv = tid >> 6;
  if ((tid & 63) == 0) { red[wv] = s; red[4 + wv] = ss; }
  __syncthreads();
  if (tid == 0) {
    s  = red[0] + red[1] + red[2] + red[3];
    ss = red[4] + red[5] + red[6] + red[7];
    const float mu  = s * (1.0f / D_MODEL);
    const float inv = rsqrtf(ss * (1.0f / D_MODEL) - mu * mu + 1e-5f);
    stats[row] = make_float2(mu, inv);
  }
}

// ---------- full LayerNorm (LN2), bf16 out ----------
__global__ __launch_bounds__(256)
void ln_kernel_bf16(const float* __restrict__ in, const float* __restrict__ gamma,
                    const float* __restrict__ beta, unsigned short* __restrict__ outp) {
  const int row = blockIdx.x;
  const int tid = threadIdx.x;
  const float4 v = reinterpret_cast<const float4*>(in + (size_t)row * D_MODEL)[tid];
  float s  = v.x + v.y + v.z + v.w;
  float ss = v.x*v.x + v.y*v.y + v.z*v.z + v.w*v.w;
  #pragma unroll
  for (int o = 32; o > 0; o >>= 1) {
    s  += __shfl_down(s, o, 64);
    ss += __shfl_down(ss, o, 64);
  }
  __shared__ float red[8];
  const int wv = tid >> 6;
  if ((tid & 63) == 0) { red[wv] = s; red[4 + wv] = ss; }
  __syncthreads();
  s  = red[0] + red[1] + red[2] + red[3];
  ss = red[4] + red[5] + red[6] + red[7];
  const float mu  = s * (1.0f / D_MODEL);
  const float inv = rsqrtf(ss * (1.0f / D_MODEL) - mu * mu + 1e-5f);
  const float4 g4 = reinterpret_cast<const float4*>(gamma)[tid];
  const float4 b4 = reinterpret_cast<const float4*>(beta)[tid];
  ushort4 o = { f2bf((v.x - mu) * inv * g4.x + b4.x),
                f2bf((v.y - mu) * inv * g4.y + b4.y),
                f2bf((v.z - mu) * inv * g4.z + b4.z),
                f2bf((v.w - mu) * inv * g4.w + b4.w) };
  reinterpret_cast<ushort4*>(outp + (size_t)row * D_MODEL)[tid] = o;
}

// ---------- SSM scan, chunked (3 phases), LN1 fused via stats ----------
__global__ __launch_bounds__(256)
void scan_phase1(const float* __restrict__ x, const float2* __restrict__ stats,
                 const float* __restrict__ ln_w, const float* __restrict__ ln_b,
                 const float* __restrict__ A_log, const float* __restrict__ B_mat,
                 float* __restrict__ hend) {
  const int d = blockIdx.x * 256 + threadIdx.x;
  const int c = blockIdx.y;
  const int b = blockIdx.z;
  float a[16], Bm[16], h[16];
  const float4* Ar = reinterpret_cast<const float4*>(A_log + d * 16);
  const float4* Br = reinterpret_cast<const float4*>(B_mat + d * 16);
  #pragma unroll
  for (int i = 0; i < 4; i++) {
    const float4 av = Ar[i], bv = Br[i];
    a[4*i+0]=av.x; a[4*i+1]=av.y; a[4*i+2]=av.z; a[4*i+3]=av.w;
    Bm[4*i+0]=bv.x; Bm[4*i+1]=bv.y; Bm[4*i+2]=bv.z; Bm[4*i+3]=bv.w;
  }
  #pragma unroll
  for (int n = 0; n < 16; n++) { a[n] = 1.0f/(1.0f+__expf(-a[n])); h[n] = 0.0f; }
  const float gd = ln_w[d], bd = ln_b[d];

  const float* xp = x + ((size_t)b * SEQ + (size_t)c * TCHUNK) * D_MODEL + d;
  const float2* sp = stats + (size_t)b * SEQ + (size_t)c * TCHUNK;
  #pragma unroll 4
  for (int t = 0; t < TCHUNK; ++t) {
    const float2 st = sp[t];
    const float xv = (xp[(size_t)t * D_MODEL] - st.x) * st.y * gd + bd;
    #pragma unroll
    for (int n = 0; n < 16; n++) h[n] = a[n]*h[n] + Bm[n]*xv;
  }
  float* hp = hend + (((size_t)b * NCHUNK + c) * D_MODEL + d) * 16;
  #pragma unroll
  for (int i = 0; i < 4; i++) {
    float4 o = { h[4*i+0], h[4*i+1], h[4*i+2], h[4*i+3] };
    reinterpret_cast<float4*>(hp)[i] = o;
  }
}

__global__ __launch_bounds__(256)
void scan_phase2(const float* __restrict__ A_log, const float* __restrict__ hend,
                 float* __restrict__ carry) {
  const int idx = blockIdx.x * 256 + threadIdx.x;
  const int n = idx & 15;
  const int d = (idx >> 4) & (D_MODEL - 1);
  const int b = idx >> 14;
  const float a = 1.0f/(1.0f+__expf(-A_log[d*16+n]));
  float aT = a;
  #pragma unroll
  for (int i = 0; i < 6; i++) aT *= aT;   // a^64
  float cv = 0.0f;
  for (int c = 0; c < NCHUNK; c++) {
    const size_t off = (((size_t)b * NCHUNK + c) * D_MODEL + d) * 16 + n;
    carry[off] = cv;
    cv = aT * cv + hend[off];
  }
}

__global__ __launch_bounds__(256)
void scan_phase3(const float* __restrict__ x, const float2* __restrict__ stats,
                 const float* __restrict__ ln_w, const float* __restrict__ ln_b,
                 const float* __restrict__ A_log, const float* __restrict__ B_mat,
                 const float* __restrict__ C_mat, const float* __restrict__ D_vec,
                 const float* __restrict__ carry, unsigned short* __restrict__ ybf) {
  const int d = blockIdx.x * 256 + threadIdx.x;
  const int c = blockIdx.y;
  const int b = blockIdx.z;
  float a[16], Bm[16], Cm[16], h[16];
  const float4* Ar = reinterpret_cast<const float4*>(A_log + d * 16);
  const float4* Br = reinterpret_cast<const float4*>(B_mat + d * 16);
  const float4* Cr = reinterpret_cast<const float4*>(C_mat + d * 16);
  const float4* Hr = reinterpret_cast<const float4*>(carry + (((size_t)b * NCHUNK + c) * D_MODEL + d) * 16);
  #pragma unroll
  for (int i = 0; i < 4; i++) {
    const float4 av = Ar[i], bv = Br[i], cv = Cr[i], hv = Hr[i];
    a[4*i+0]=av.x; a[4*i+1]=av.y; a[4*i+2]=av.z; a[4*i+3]=av.w;
    Bm[4*i+0]=bv.x; Bm[4*i+1]=bv.y; Bm[4*i+2]=bv.z; Bm[4*i+3]=bv.w;
    Cm[4*i+0]=cv.x; Cm[4*i+1]=cv.y; Cm[4*i+2]=cv.z; Cm[4*i+3]=cv.w;
    h[4*i+0]=hv.x; h[4*i+1]=hv.y; h[4*i+2]=hv.z; h[4*i+3]=hv.w;
  }
  #pragma unroll
  for (int n = 0; n < 16; n++) a[n] = 1.0f/(1.0f+__expf(-a[n]));
  const float Dv = D_vec[d];
  const float gd = ln_w[d], bd = ln_b[d];

  const float* xp = x + ((size_t)b * SEQ + (size_t)c * TCHUNK) * D_MODEL + d;
  const float2* sp = stats + (size_t)b * SEQ + (size_t)c * TCHUNK;
  unsigned short* yp = ybf + ((size_t)b * SEQ + (size_t)c * TCHUNK) * D_MODEL + d;
  #pragma unroll 4
  for (int t = 0; t < TCHUNK; ++t) {
    const float2 st = sp[t];
    const float xv = (xp[(size_t)t * D_MODEL] - st.x) * st.y * gd + bd;
    float y = Dv * xv;
    #pragma unroll
    for (int n = 0; n < 16; n++) {
      h[n] = a[n]*h[n] + Bm[n]*xv;
      y += Cm[n]*h[n];
    }
    yp[(size_t)t * D_MODEL] = f2bf(y / (1.0f + __expf(-y)));
  }
}

// ---------- deep-pipelined bf16 MFMA GEMM ----------
// C[M,N] = epi(A[M,K] @ Bt[N,K]^T + bias); BM=256 fixed, BN in {128,256}, BK=64.
// 512 thr = 8 waves (2 Mrow-groups x 4 Ncol-groups). Double-buffered LDS,
// counted vmcnt (loads for tile t+1 in flight across barriers), XOR-swizzled
// LDS reads (conflict-free), raw s_barrier, setprio around MFMA cluster.
template<int BN, int ACT, bool RES, typename OutT>
__global__ __launch_bounds__(512, 2)
void gemm_dp(const unsigned short* __restrict__ A, const unsigned short* __restrict__ Bt,
             const float* __restrict__ bias, const float* __restrict__ res,
             OutT* __restrict__ C, int M, int N, int K) {
  constexpr int BM = 256;
  constexpr int BK = 64;                 // 128 bytes per LDS row
  constexpr int RA = BM / 64;            // A stage rounds (4)
  constexpr int RB = BN / 64;            // B stage rounds (2 or 4)
  constexpr int NL = RA + RB;            // loads/wave/tile = vmcnt target
  constexpr int NR = BN / 64;            // N fragments per wave

  __shared__ unsigned short As[2][BM * BK];
  __shared__ unsigned short Bs[2][BN * BK];

  const int tid = threadIdx.x;
  const int l   = tid & 63;
  const int w   = tid >> 6;
  const int wr  = w >> 2;                // 0..1
  const int wn  = w & 3;                 // 0..3

  // XCD-aware chunked swizzle (grid divisible by 8)
  const int nbx = N / BN;
  int bid = blockIdx.x;
  const int cpx = gridDim.x >> 3;
  bid = (bid & 7) * cpx + (bid >> 3);
  const int bn = (bid % nbx) * BN;
  const int bm = (bid / nbx) * BM;

  // staging: round r, wave w covers LDS bytes [(r*8+w)*1024, +1024); lane l at +l*16.
  // LDS row = (r*8+w)*8 + (l>>3), col-byte kb = (l&7)*16. Content must be
  // global[row][kb ^ ((row&7)<<4)]  (row&7 == l>>3 here).
  const int srow = l >> 3;                              // row offset within 8
  const int skb  = ((l & 7) ^ (l >> 3)) << 4;           // pre-swizzled source byte
  const char* Agbase = (const char*)A  + (size_t)bm * K * 2 + skb;
  const char* Bgbase = (const char*)Bt + (size_t)bn * K * 2 + skb;

  // read-side lane constants: frag addr = base + row*128 + (kb_lin ^ ((row&7)<<4))
  // row&7 == l&7 for all fragments (row = 16-aligned + (l&15))
  const int xk0 = (((l >> 4) << 4)     ) ^ ((l & 7) << 4);
  const int xk1 = (((l >> 4) << 4) + 64) ^ ((l & 7) << 4);
  const char* ArdBase0 = (const char*)As[0] + (size_t)(wr * 128 + (l & 15)) * 128;
  const char* ArdBase1 = (const char*)As[1] + (size_t)(wr * 128 + (l & 15)) * 128;
  const char* BrdBase0 = (const char*)Bs[0] + (size_t)(wn * (BN / 4) + (l & 15)) * 128;
  const char* BrdBase1 = (const char*)Bs[1] + (size_t)(wn * (BN / 4) + (l & 15)) * 128;

  f32x4 acc[8][NR] = {};

  auto stage = [&](int buf, int k0) {
    #pragma unroll
    for (int r = 0; r < RA; ++r) {
      const int row = (r * 8 + w) * 8 + srow;
      gload_lds16(Agbase + ((size_t)row * K + k0) * 2,
                  (char*)As[buf] + (r * 8 + w) * 1024);
    }
    #pragma unroll
    for (int r = 0; r < RB; ++r) {
      const int row = (r * 8 + w) * 8 + srow;
      gload_lds16(Bgbase + ((size_t)row * K + k0) * 2,
                  (char*)Bs[buf] + (r * 8 + w) * 1024);
    }
  };

  auto compute = [&](int buf) {
    const char* Ap = buf ? ArdBase1 : ArdBase0;
    const char* Bp = buf ? BrdBase1 : BrdBase0;
    #pragma unroll
    for (int kk = 0; kk < 2; ++kk) {
      const int xk = kk ? xk1 : xk0;
      short8 af[8];
      #pragma unroll
      for (int m = 0; m < 8; ++m)
        af[m] = *reinterpret_cast<const short8*>(Ap + m * 2048 + xk);
      short8 bfv[NR];
      #pragma unroll
      for (int n = 0; n < NR; ++n)
        bfv[n] = *reinterpret_cast<const short8*>(Bp + n * 2048 + xk);
      __builtin_amdgcn_s_setprio(1);
      #pragma unroll
      for (int m = 0; m < 8; ++m)
        #pragma unroll
        for (int n = 0; n < NR; ++n)
          acc[m][n] = __builtin_amdgcn_mfma_f32_16x16x32_bf16(af[m], bfv[n], acc[m][n], 0, 0, 0);
      __builtin_amdgcn_s_setprio(0);
    }
  };

  const int NT = K / BK;
  stage(0, 0);
  for (int t = 0; t < NT - 1; ++t) {
    stage((t + 1) & 1, (t + 1) * BK);                     // prefetch next tile
    asm volatile("s_waitcnt vmcnt(%0)" :: "i"(NL) : "memory");  // tile t landed (ours)
    __builtin_amdgcn_s_barrier();                         // tile t landed (all waves)
    asm volatile("" ::: "memory");
    compute(t & 1);
    asm volatile("" ::: "memory");
    __builtin_amdgcn_s_barrier();                         // reads of buf done before next writes
  }
  asm volatile("s_waitcnt vmcnt(0)" ::: "memory");
  __builtin_amdgcn_s_barrier();
  asm volatile("" ::: "memory");
  compute((NT - 1) & 1);

  // epilogue: D row=(l>>4)*4+r, col=l&15
  const int fr = (l >> 4) * 4;
  const int fc = l & 15;
  #pragma unroll
  for (int n = 0; n < NR; ++n) {
    const int col = bn + wn * (BN / 4) + n * 16 + fc;
    const float bv = bias[col];
    #pragma unroll
    for (int m = 0; m < 8; ++m) {
      const int row0 = bm + wr * 128 + m * 16 + fr;
      #pragma unroll
      for (int r = 0; r < 4; ++r) {
        const size_t idx = (size_t)(row0 + r) * N + col;
        float v = acc[m][n][r] + bv;
        if (ACT == 1) v = 0.5f * v * (1.0f + erff(v * 0.70710678118f));
        if (RES) v += res[idx];
        if constexpr (sizeof(OutT) == 2) C[idx] = (OutT)f2bf(v);
        else                             C[idx] = v;
      }
    }
  }
}

// ---------- launch ----------
extern "C" void kernel_launch(void* const* d_in, const int* in_sizes, int n_in,
                              void* d_out, int out_size, void* d_ws, size_t ws_size,
                              hipStream_t stream) {
  const float* x      = (const float*)d_in[0];
  const float* ln_w   = (const float*)d_in[1];
  const float* ln_b   = (const float*)d_in[2];
  const float* A_log  = (const float*)d_in[3];
  const float* B_mat  = (const float*)d_in[4];
  const float* C_mat  = (const float*)d_in[5];
  const float* D_vec  = (const float*)d_in[6];
  const float* out_w  = (const float*)d_in[7];
  const float* out_b  = (const float*)d_in[8];
  const float* ln2_w  = (const float*)d_in[9];
  const float* ln2_b  = (const float*)d_in[10];
  const float* ffn1_w = (const float*)d_in[11];
  const float* ffn1_b = (const float*)d_in[12];
  const float* ffn2_w = (const float*)d_in[13];
  const float* ffn2_b = (const float*)d_in[14];
  float* out = (float*)d_out;

  char* ws = (char*)d_ws;
  const size_t MB = 1u << 20;
  float*          x1    = (float*)(ws);                    // 32MB (GEMM1 out)
  unsigned short* ybf   = (unsigned short*)(ws + 32*MB);   // 16MB; reused as xn2
  unsigned short* hdn   = (unsigned short*)(ws + 48*MB);   // 64MB
  unsigned short* w1b   = (unsigned short*)(ws + 112*MB);  // 2MB
  unsigned short* w2b   = (unsigned short*)(ws + 114*MB);  // 8MB
  unsigned short* w3b   = (unsigned short*)(ws + 122*MB);  // 8MB
  float*          hend  = (float*)(ws + 130*MB);           // 8MB
  float*          carry = (float*)(ws + 138*MB);           // 8MB
  float2*         stats = (float2*)(ws + 146*MB);          // 64KB

  // weights -> bf16
  cvt_bf16<<<(D_MODEL*D_MODEL/4)/256, 256, 0, stream>>>(out_w,  w1b, D_MODEL*D_MODEL/4);
  cvt_bf16<<<(H_FFN*D_MODEL/4)/256,  256, 0, stream>>>(ffn1_w, w2b, H_FFN*D_MODEL/4);
  cvt_bf16<<<(H_FFN*D_MODEL/4)/256,  256, 0, stream>>>(ffn2_w, w3b, H_FFN*D_MODEL/4);

  // LN1 stats (normalize fused into scan)
  ln_stats<<<M_ROWS, 256, 0, stream>>>(x, stats);

  // SSM scan -> ybf = silu(y) bf16
  dim3 gscan(D_MODEL/256, NCHUNK, BATCH);
  scan_phase1<<<gscan, 256, 0, stream>>>(x, stats, ln_w, ln_b, A_log, B_mat, hend);
  scan_phase2<<<(BATCH*D_MODEL*N_STATE)/256, 256, 0, stream>>>(A_log, hend, carry);
  scan_phase3<<<gscan, 256, 0, stream>>>(x, stats, ln_w, ln_b, A_log, B_mat, C_mat,
                                         D_vec, carry, ybf);

  // GEMM1: x1 = x + silu_y @ out_w^T + out_b   (BN=128: grid 256)
  gemm_dp<128, 0, true, float><<<dim3((M_ROWS/256)*(D_MODEL/128)), 512, 0, stream>>>(
      ybf, w1b, out_b, x, x1, M_ROWS, D_MODEL, D_MODEL);

  // LN2: xn2 = LN(x1) bf16 (into ybf buffer)
  ln_kernel_bf16<<<M_ROWS, 256, 0, stream>>>(x1, ln2_w, ln2_b, ybf);

  // GEMM2: hdn = gelu(xn2 @ ffn1^T + ffn1_b) bf16  (BN=256: grid 512)
  gemm_dp<256, 1, false, unsigned short><<<dim3((M_ROWS/256)*(H_FFN/256)), 512, 0, stream>>>(
      ybf, w2b, ffn1_b, nullptr, hdn, M_ROWS, H_FFN, D_MODEL);

  // GEMM3: out = x1 + hdn @ ffn2^T + ffn2_b (BN=128: grid 256)
  gemm_dp<128, 0, true, float><<<dim3((M_ROWS/256)*(D_MODEL/128)), 512, 0, stream>>>(
      hdn, w3b, ffn2_b, x1, out, M_ROWS, D_MODEL, H_FFN);
}